// Round 3
// baseline (632.302 us; speedup 1.0000x reference)
//
#include <hip/hip_runtime.h>

// MultiHeadAttention fused block, MI355X gfx950.
// B=256, NA=128, E=1024, H=16, HD=64. M = B*NA = 32768 rows.
//
// Pipeline:
//   K0: in_w fp32 -> bf16                   (Wb)
//   K1: LN1(x) -> bf16                      (xnb), wave-per-row
//   K2: MFMA GEMM xnb @ Wb^T + bias -> Qb(.125 folded), Kb, Vb (bf16)
//       256x256 tile, BK=64, 8-phase counted-vmcnt schedule; swizzled epilogue
//   K2b: Vb -> Vt ([j][d][i]) in-register 8x8 transpose (overlays xnb region)
//   K3: per-group attention, 2 groups/block, 2 waves/group (wave owns 64 rows
//       x all 128 cols). Swapped S' = K Q^T -> in-wave softmax (2 shuffles,
//       no barriers), per-wave private P panel in reclaimed LDS, PV from Vt.
//       3 barriers total (was 6).
//   K4: recompute LN1 stats, residual + LN2 -> d_out, wave-per-row
//
// Workspace layout (bytes):
//   [0,            67108864)  xnb (K2 input) -> Vt (K2b output)   -- reused
//   [67108864,    134217728)  Qb
//   [134217728,   201326592)  Kb
//   [201326592,   268435456)  Vb (K2 out) -> attnb (K3 out)       -- reused
//   [268435456,   274726912)  Wb (3072*1024 bf16)
// Total 274.7 MB.

typedef __attribute__((ext_vector_type(4))) float float4v;
typedef __attribute__((ext_vector_type(4))) int   int4v;
typedef __attribute__((ext_vector_type(8))) short short8v;
typedef __attribute__((ext_vector_type(4))) short short4v;

#define LN_EPS 1e-5f

// Direct global->LDS DMA, 16 B per lane. LDS base must be wave-uniform;
// hardware writes base + lane*16.
#define GLL(g, l) __builtin_amdgcn_global_load_lds( \
    (const __attribute__((address_space(1))) unsigned int*)(g), \
    (__attribute__((address_space(3))) unsigned int*)(l), 16, 0, 0)

__device__ __forceinline__ unsigned short f2bf(float f) {
    unsigned int u = __float_as_uint(f);
    u += 0x7FFFu + ((u >> 16) & 1u);   // round-to-nearest-even
    return (unsigned short)(u >> 16);
}
__device__ __forceinline__ float bf2f(unsigned short h) {
    return __uint_as_float(((unsigned int)h) << 16);
}
__device__ __forceinline__ unsigned int pk_bf16(float lo, float hi) {
    unsigned int r;
    asm("v_cvt_pk_bf16_f32 %0, %1, %2" : "=v"(r) : "v"(lo), "v"(hi));
    return r;
}

// ---------------------------------------------------------------- K0: W->bf16
__global__ __launch_bounds__(256) void k0_w_to_bf16(const float* __restrict__ w,
                                                    unsigned short* __restrict__ wb) {
    int idx = blockIdx.x * 256 + threadIdx.x;      // one thread per 8 elems
    const float4v* src = (const float4v*)w;
    float4v a = src[idx * 2];
    float4v b = src[idx * 2 + 1];
    short8v o;
    o[0] = (short)f2bf(a[0]); o[1] = (short)f2bf(a[1]);
    o[2] = (short)f2bf(a[2]); o[3] = (short)f2bf(a[3]);
    o[4] = (short)f2bf(b[0]); o[5] = (short)f2bf(b[1]);
    o[6] = (short)f2bf(b[2]); o[7] = (short)f2bf(b[3]);
    *((short8v*)wb + idx) = o;
}

// ---------------------------------------------------------------- K1: LN1
// Wave-per-row: 4 rows/block, pure shfl reduction, no LDS / no syncthreads.
__global__ __launch_bounds__(256) void k1_ln1(const float* __restrict__ x,
                                              const float* __restrict__ w1,
                                              const float* __restrict__ b1,
                                              unsigned short* __restrict__ xnb) {
    int lane = threadIdx.x & 63;
    int wave = threadIdx.x >> 6;
    int row  = blockIdx.x * 4 + wave;
    const float4v* xr = (const float4v*)(x + (size_t)row * 1024);
    float4v xv[4];
    float s = 0.f, s2 = 0.f;
    #pragma unroll
    for (int c = 0; c < 4; ++c) {
        xv[c] = xr[c * 64 + lane];
        #pragma unroll
        for (int e = 0; e < 4; ++e) { s += xv[c][e]; s2 += xv[c][e] * xv[c][e]; }
    }
    #pragma unroll
    for (int off = 32; off > 0; off >>= 1) {
        s  += __shfl_xor(s, off, 64);
        s2 += __shfl_xor(s2, off, 64);
    }
    float mean = s * (1.0f / 1024.0f);
    float var  = s2 * (1.0f / 1024.0f) - mean * mean;
    float rs   = rsqrtf(var + LN_EPS);
    #pragma unroll
    for (int c = 0; c < 4; ++c) {
        int idx = c * 64 + lane;
        float4v wv = ((const float4v*)w1)[idx];
        float4v bv = ((const float4v*)b1)[idx];
        short4v o;
        #pragma unroll
        for (int e = 0; e < 4; ++e)
            o[e] = (short)f2bf((xv[c][e] - mean) * rs * wv[e] + bv[e]);
        ((short4v*)(xnb + (size_t)row * 1024))[idx] = o;
    }
}

// ---------------------------------------------------------------- K2: QKV GEMM
// C[m][n] = sum_k A[m][k]*W[n][k] + bias[n]; A:32768x1024 bf16, W:3072x1024 bf16.
// 256x256 tile, BK=64, 8 waves (2M x 4N), per-wave 128x64 output (acc[8][4]).
// LDS 128 KiB: sA[2]/sB[2] double-buffered [256][64] bf16 K-tiles.
// T2 swizzle: logical (row, colByte cb) lives at physical cb ^ ((row&7)<<4);
// global_load_lds writes linearly, so the global SOURCE col is pre-XORed.
// 8 phases/iter, counted vmcnt(4) at ph4/ph8 only (see round-1 derivation).
__global__ __launch_bounds__(512, 2) void k2_qkv_gemm(const unsigned short* __restrict__ A,
                                                      const unsigned short* __restrict__ W,
                                                      const float* __restrict__ bias,
                                                      unsigned short* __restrict__ Qb,
                                                      unsigned short* __restrict__ Kb,
                                                      unsigned short* __restrict__ Vb) {
    __shared__ unsigned short smem[65536];           // 128 KiB (also epilogue C-tile)
    unsigned short* sA0 = smem;                      // [256][64] bf16, even K-tile
    unsigned short* sA1 = smem + 16384;              // odd K-tile
    unsigned short* sB0 = smem + 32768;
    unsigned short* sB1 = smem + 49152;

    int bid = blockIdx.x;
    int wg  = (bid & 7) * 192 + (bid >> 3);          // XCD swizzle, 1536 % 8 == 0 (bijective)
    int nT  = wg % 12;                               // N-fastest: 12 consecutive share A panel
    int mT  = wg / 12;
    int rowBase = mT * 256;
    int colBase = nT * 256;

    int tid  = threadIdx.x;
    int lane = tid & 63;
    int wave = tid >> 6;
    int wm = wave >> 2, wn = wave & 3;               // 2 x 4 wave grid
    int q4 = lane >> 4, l15 = lane & 15;

    // staging: thread t stages physical LDS bytes [r*8192 + t*16, +16):
    // row = r*64 + t/8, physBy = (t&7)*16; source colByte = physBy ^ ((row&7)<<4).
    int lrow_s = tid >> 3;                           // row within 64-row round
    int srcCol = ((tid & 7) * 16) ^ ((lrow_s & 7) << 4);
    const char* aSrc = (const char*)A + ((size_t)(rowBase + lrow_s) << 11) + srcCol;
    const char* wSrc = (const char*)W + ((size_t)(colBase + lrow_s) << 11) + srcCol;
    int waveOff = wave * 1024;

    // fragment read offsets (bytes): row*128 + ((kk*64 + q4*16) ^ ((l15&7)<<4))
    int xorv = (l15 & 7) << 4;
    int aRow = (wm * 128 + l15) * 128;
    int bRow = (wn * 64 + l15) * 128;
    int bc0 = (q4 * 16) ^ xorv;                      // kk = 0
    int bc1 = (64 + q4 * 16) ^ xorv;                 // kk = 1

    float bv[4];
    #pragma unroll
    for (int n = 0; n < 4; ++n) bv[n] = bias[colBase + wn * 64 + n * 16 + l15];

    float4v acc[8][4];
    #pragma unroll
    for (int t = 0; t < 8; ++t)
        #pragma unroll
        for (int n = 0; n < 4; ++n) acc[t][n] = (float4v){0.f, 0.f, 0.f, 0.f};

#define STAGE_HALF(lds, src, ktB_, h) do { \
    GLL((src) + (ktB_) + (2*(h))   * 131072, (char*)(lds) + (2*(h))   * 8192 + waveOff); \
    GLL((src) + (ktB_) + (2*(h)+1) * 131072, (char*)(lds) + (2*(h)+1) * 8192 + waveOff); \
} while (0)
#define LDB(SB) do { \
    const char* c_ = (const char*)(SB); \
    _Pragma("unroll") \
    for (int n = 0; n < 4; ++n) { \
        bf[n][0] = *(const short8v*)(c_ + bRow + n * 2048 + bc0); \
        bf[n][1] = *(const short8v*)(c_ + bRow + n * 2048 + bc1); \
    } \
} while (0)
#define LDA2(SA, T0_) do { \
    const char* c_ = (const char*)(SA); \
    af[0][0] = *(const short8v*)(c_ + aRow + (T0_)     * 2048 + bc0); \
    af[0][1] = *(const short8v*)(c_ + aRow + (T0_)     * 2048 + bc1); \
    af[1][0] = *(const short8v*)(c_ + aRow + (T0_ + 1) * 2048 + bc0); \
    af[1][1] = *(const short8v*)(c_ + aRow + (T0_ + 1) * 2048 + bc1); \
} while (0)
#define MFMA8(T0_) do { \
    __builtin_amdgcn_s_setprio(1); \
    _Pragma("unroll") \
    for (int n = 0; n < 4; ++n) { \
        acc[T0_][n]     = __builtin_amdgcn_mfma_f32_16x16x32_bf16(af[0][0], bf[n][0], acc[T0_][n], 0, 0, 0); \
        acc[T0_][n]     = __builtin_amdgcn_mfma_f32_16x16x32_bf16(af[0][1], bf[n][1], acc[T0_][n], 0, 0, 0); \
        acc[T0_ + 1][n] = __builtin_amdgcn_mfma_f32_16x16x32_bf16(af[1][0], bf[n][0], acc[T0_ + 1][n], 0, 0, 0); \
        acc[T0_ + 1][n] = __builtin_amdgcn_mfma_f32_16x16x32_bf16(af[1][1], bf[n][1], acc[T0_ + 1][n], 0, 0, 0); \
    } \
    __builtin_amdgcn_s_setprio(0); \
} while (0)
#define PH_SYNC do { __builtin_amdgcn_s_barrier(); asm volatile("s_waitcnt lgkmcnt(0)"); } while (0)
#define PH_END  __builtin_amdgcn_s_barrier()

    // prologue: T0 full (A+B) + T1.B; leave T1.B (4 loads) in flight
    STAGE_HALF(sA0, aSrc, 0, 0);
    STAGE_HALF(sA0, aSrc, 0, 1);
    STAGE_HALF(sB0, wSrc, 0, 0);
    STAGE_HALF(sB0, wSrc, 0, 1);
    STAGE_HALF(sB1, wSrc, 128, 0);
    STAGE_HALF(sB1, wSrc, 128, 1);
    asm volatile("s_waitcnt vmcnt(4)");
    __builtin_amdgcn_s_barrier();

    short8v af[2][2], bf[4][2];

    #pragma unroll 1
    for (int i = 0; i < 8; ++i) {
        int ktB = i << 8;                 // byte K-offset of T(2i) (tile = 128 B)
        bool nl = (i < 7);
        // PH1: T(2i) quad0 from buf0; stage T(2i+1).A0 -> buf1
        LDB(sB0); LDA2(sA0, 0);
        STAGE_HALF(sA1, aSrc, ktB + 128, 0);
        PH_SYNC; MFMA8(0); PH_END;
        // PH2: quad1; stage T(2i+1).A1
        LDA2(sA0, 2);
        STAGE_HALF(sA1, aSrc, ktB + 128, 1);
        PH_SYNC; MFMA8(2); PH_END;
        // PH3: quad2; stage T(2i+2).B0
        LDA2(sA0, 4);
        if (nl) STAGE_HALF(sB0, wSrc, ktB + 256, 0);
        PH_SYNC; MFMA8(4); PH_END;
        // PH4: quad3; stage T(2i+2).B1; counted wait -> T(2i+1) fully landed
        LDA2(sA0, 6);
        if (nl) { STAGE_HALF(sB0, wSrc, ktB + 256, 1); asm volatile("s_waitcnt vmcnt(4)"); }
        else    { asm volatile("s_waitcnt vmcnt(0)"); }
        PH_SYNC; MFMA8(6); PH_END;
        // PH5: T(2i+1) quad0 from buf1; stage T(2i+2).A0
        LDB(sB1); LDA2(sA1, 0);
        if (nl) STAGE_HALF(sA0, aSrc, ktB + 256, 0);
        PH_SYNC; MFMA8(0); PH_END;
        // PH6: quad1; stage T(2i+2).A1
        LDA2(sA1, 2);
        if (nl) STAGE_HALF(sA0, aSrc, ktB + 256, 1);
        PH_SYNC; MFMA8(2); PH_END;
        // PH7: quad2; stage T(2i+3).B0
        LDA2(sA1, 4);
        if (nl) STAGE_HALF(sB1, wSrc, ktB + 384, 0);
        PH_SYNC; MFMA8(4); PH_END;
        // PH8: quad3; stage T(2i+3).B1; counted wait -> T(2i+2) fully landed
        LDA2(sA1, 6);
        if (nl) { STAGE_HALF(sB1, wSrc, ktB + 384, 1); asm volatile("s_waitcnt vmcnt(4)"); }
        PH_SYNC; MFMA8(6); PH_END;
    }
#undef STAGE_HALF
#undef LDB
#undef LDA2
#undef MFMA8
#undef PH_SYNC
#undef PH_END

    // Epilogue: bias+scale, bf16 C-tile through LDS for coalesced 16B stores.
    // XOR-swizzled LDS slots; un-permute on the global store side.
    __syncthreads();
    float scale = (colBase < 1024) ? 0.125f : 1.0f;
    unsigned short* outb = (colBase < 1024) ? Qb : (colBase < 2048) ? Kb : Vb;
    int lcol = colBase & 1023;
    #pragma unroll
    for (int t = 0; t < 8; ++t)
        #pragma unroll
        for (int n = 0; n < 4; ++n)
            #pragma unroll
            for (int g = 0; g < 4; ++g) {
                int row  = wm * 128 + t * 16 + q4 * 4 + g;
                int colb = (wn * 64 + n * 16 + l15) * 2;
                *(unsigned short*)((char*)smem + row * 512 + (colb ^ ((row & 7) << 4))) =
                    f2bf((acc[t][n][g] + bv[n]) * scale);
            }
    __syncthreads();
    #pragma unroll
    for (int k = 0; k < 16; ++k) {
        int r = k * 16 + (tid >> 5);                 // half-wave = one 512B row chunk
        short8v v = *(const short8v*)((const char*)smem + r * 512 + (tid & 31) * 16);
        int colb = ((tid & 31) * 16) ^ ((r & 7) << 4);
        *(short8v*)((char*)(outb + (size_t)(rowBase + r) * 1024 + lcol) + colb) = v;
    }
}

// ---------------------------------------------------------------- K2b: V -> Vt
// Vb element [i][j*64+d] at flat i*262144 + j*64 + d  (i<128, j<4096, d<64).
// Vt element [j][d][i]   at flat j*8192 + d*128 + i.
// In-register 8x8 transpose; reads 16B/lane, writes 16B/lane coalesced.
__global__ __launch_bounds__(256) void k2b_vtrans(const unsigned short* __restrict__ Vb,
                                                  unsigned short* __restrict__ Vt) {
    int g  = blockIdx.x * 256 + threadIdx.x;        // 8x8 tile id
    int ib = g & 15;                                // i0 = ib*8
    int db = (g >> 4) & 7;                          // d0 = db*8
    int j  = g >> 7;
    const unsigned short* src = Vb + (size_t)(ib * 8) * 262144 + (size_t)j * 64 + db * 8;
    short8v in[8];
    #pragma unroll
    for (int r = 0; r < 8; ++r)
        in[r] = *(const short8v*)(src + (size_t)r * 262144);
    unsigned short* dst = Vt + (size_t)j * 8192 + (db * 8) * 128 + ib * 8;
    #pragma unroll
    for (int c = 0; c < 8; ++c) {
        short8v o;
        #pragma unroll
        for (int r = 0; r < 8; ++r) o[r] = in[r][c];
        *(short8v*)(dst + c * 128) = o;
    }
}

// ---------------------------------------------------------------- K3: attention
// 2048 blocks, 2 groups/block (j = 2*bid + grp), 2 waves/group; wave (grp,wm)
// owns rows m in [wm*64, wm*64+64) x all 128 cols of group j.
// Swapped S' = K Q^T: C-layout col = m = l15 -> row-softmax over n is in-lane
// (8 tn-tiles x 4 regs) + shfl_xor(16,32) across q4. No cross-wave reductions.
// P panel per wave: private LDS [64 m][136 n] bf16 (272B rows, padded — banks
// naturally spread, b128-aligned). Barriers: stage, LDS-reclaim, avgw-combine.
__global__ __launch_bounds__(256) void k3_attn(const unsigned short* __restrict__ Qb,
                                               const unsigned short* __restrict__ Kb,
                                               const unsigned short* __restrict__ Vt,
                                               unsigned short* __restrict__ attnb,
                                               float* __restrict__ avgw) {
    __shared__ unsigned short smem[34816];   // 69632 B: sQ[2]|sK[2] 64KB -> sP[4 waves][64][136]
    __shared__ float csum[2][2][128];        // [wm][grp][n]

    int tid = threadIdx.x;
    int lane = tid & 63;
    int wave = tid >> 6;
    int grp = wave >> 1, wm = wave & 1;
    int j = blockIdx.x * 2 + grp;
    int q4 = lane >> 4, l15 = lane & 15;

    unsigned short* sQ = smem + grp * 8192;            // [128][64] bf16, swizzled cols
    unsigned short* sK = smem + 16384 + grp * 8192;
    char* sP = (char*)smem + wave * 17408;             // [64][136] bf16, plain padded

    csum[0][tid >> 7][tid & 127] = 0.f;
    csum[1][tid >> 7][tid & 127] = 0.f;

    // Stage Q,K rows [wm*64, wm*64+64) of group j via GLL; linear LDS dest,
    // source col XOR-pre-swizzled (row&7 == lane>>3 within each 8-row GLL).
    {
        const char* qg = (const char*)(Qb + (size_t)j * 64);
        const char* kg = (const char*)(Kb + (size_t)j * 64);
        int swz = ((lane & 7) ^ (lane >> 3)) << 4;
        #pragma unroll
        for (int blk = 0; blk < 8; ++blk) {
            int row0 = wm * 64 + blk * 8;
            size_t src = (size_t)(row0 + (lane >> 3)) * 524288 + swz;
            GLL(qg + src, (char*)sQ + row0 * 128);
            GLL(kg + src, (char*)sK + row0 * 128);
        }
    }
    __syncthreads();                                   // barrier 1 (drains GLL)

    // S'[n][m] = K Q^T: tiles S[tn=8][tm=4]; per-lane n = tn*16+q4*4+g, m = tm*16+l15.
    float4v S[8][4];
    #pragma unroll
    for (int a = 0; a < 8; ++a)
        #pragma unroll
        for (int b = 0; b < 4; ++b) S[a][b] = (float4v){0.f, 0.f, 0.f, 0.f};
    #pragma unroll
    for (int ks = 0; ks < 2; ++ks) {
        int cb = (ks * 64 + q4 * 16) ^ ((l15 & 7) << 4);
        short8v qf[4];
        #pragma unroll
        for (int tm = 0; tm < 4; ++tm)
            qf[tm] = *(const short8v*)((const char*)sQ + (wm * 64 + tm * 16 + l15) * 128 + cb);
        #pragma unroll
        for (int tn = 0; tn < 8; ++tn) {
            short8v kf = *(const short8v*)((const char*)sK + (tn * 16 + l15) * 128 + cb);
            #pragma unroll
            for (int tm = 0; tm < 4; ++tm)
                S[tn][tm] = __builtin_amdgcn_mfma_f32_16x16x32_bf16(kf, qf[tm], S[tn][tm], 0, 0, 0);
        }
    }
    __syncthreads();                                   // barrier 2: reclaim sQ/sK as sP

    // Prefetch first V k-slice (hidden under softmax). Vt[j][d][i]: 16B/lane.
    const char* vg = (const char*)Vt + (size_t)j * 16384;
    short8v vf0[4], vf1[4];
    #pragma unroll
    for (int t = 0; t < 4; ++t)
        vf0[t] = *(const short8v*)(vg + (t * 16 + l15) * 256 + q4 * 16);

    // In-wave softmax over n (rows of S' = cols of S): in-lane + shfl_xor(16,32).
    float rmax[4], inv[4];
    #pragma unroll
    for (int tm = 0; tm < 4; ++tm) {
        float m0 = S[0][tm][0];
        #pragma unroll
        for (int tn = 0; tn < 8; ++tn)
            #pragma unroll
            for (int g = 0; g < 4; ++g) m0 = fmaxf(m0, S[tn][tm][g]);
        m0 = fmaxf(m0, __shfl_xor(m0, 16, 64));
        m0 = fmaxf(m0, __shfl_xor(m0, 32, 64));
        rmax[tm] = m0;
    }
    #pragma unroll
    for (int tm = 0; tm < 4; ++tm) {
        float t0 = 0.f;
        #pragma unroll
        for (int tn = 0; tn < 8; ++tn)
            #pragma unroll
            for (int g = 0; g < 4; ++g) {
                float e = __expf(S[tn][tm][g] - rmax[tm]);
                S[tn][tm][g] = e;
                t0 += e;
            }
        t0 += __shfl_xor(t0, 16, 64);
        t0 += __shfl_xor(t0, 32, 64);
        inv[tm] = 1.0f / t0;
    }
    #pragma unroll
    for (int tn = 0; tn < 8; ++tn)
        #pragma unroll
        for (int tm = 0; tm < 4; ++tm)
            #pragma unroll
            for (int g = 0; g < 4; ++g) S[tn][tm][g] *= inv[tm];

    // avg_w partial colsums: sum over m = in-lane over tm + shfl_xor(1,2,4,8) over l15.
    #pragma unroll
    for (int tn = 0; tn < 8; ++tn) {
        #pragma unroll
        for (int g = 0; g < 4; ++g) {
            float cs = S[tn][0][g] + S[tn][1][g] + S[tn][2][g] + S[tn][3][g];
            cs += __shfl_xor(cs, 1, 64);
            cs += __shfl_xor(cs, 2, 64);
            cs += __shfl_xor(cs, 4, 64);
            cs += __shfl_xor(cs, 8, 64);
            if (l15 == 0) csum[wm][grp][tn * 16 + q4 * 4 + g] = cs;
        }
    }

    // P -> private LDS panel [m_l][136] bf16 via cvt_pk (u32 = 2 adjacent n).
    #pragma unroll
    for (int tn = 0; tn < 8; ++tn)
        #pragma unroll
        for (int tm = 0; tm < 4; ++tm)
            #pragma unroll
            for (int p = 0; p < 2; ++p) {
                unsigned int pk = pk_bf16(S[tn][tm][2 * p], S[tn][tm][2 * p + 1]);
                *(unsigned int*)(sP + (tm * 16 + l15) * 272 +
                                 (tn * 16 + q4 * 4 + 2 * p) * 2) = pk;
            }

    // PV: O[m][d] = sum_n P[m][n] V[n][d]; A = pf (own LDS), B = vf (Vt regs).
    float4v O[4][4];
    #pragma unroll
    for (int a = 0; a < 4; ++a)
        #pragma unroll
        for (int b = 0; b < 4; ++b) O[a][b] = (float4v){0.f, 0.f, 0.f, 0.f};
    #pragma unroll
    for (int ks = 0; ks < 4; ++ks) {
        // prefetch next V k-slice
        if (ks < 3) {
            #pragma unroll
            for (int t = 0; t < 4; ++t)
                vf1[t] = *(const short8v*)(vg + (t * 16 + l15) * 256 + (ks + 1) * 64 + q4 * 16);
        }
        short8v pf[4];
        #pragma unroll
        for (int tm = 0; tm < 4; ++tm)
            pf[tm] = *(const short8v*)(sP + (tm * 16 + l15) * 272 + ks * 64 + q4 * 16);
        #pragma unroll
        for (int tm = 0; tm < 4; ++tm)
            #pragma unroll
            for (int tno = 0; tno < 4; ++tno)
                O[tm][tno] = __builtin_amdgcn_mfma_f32_16x16x32_bf16(pf[tm], vf0[tno], O[tm][tno], 0, 0, 0);
        #pragma unroll
        for (int t = 0; t < 4; ++t) vf0[t] = vf1[t];
    }

    // Store O: attnb flat = m*262144 + j*64 + d; 32B chunks per 16 lanes.
    size_t base = (size_t)j * 64;
    #pragma unroll
    for (int tm = 0; tm < 4; ++tm)
        #pragma unroll
        for (int tno = 0; tno < 4; ++tno)
            #pragma unroll
            for (int g = 0; g < 4; ++g) {
                int m = wm * 64 + tm * 16 + q4 * 4 + g;
                int d = tno * 16 + l15;
                attnb[base + (size_t)m * 262144 + d] = f2bf(O[tm][tno][g]);
            }

    __syncthreads();                                   // barrier 3: csum combine
    {
        int g2 = tid >> 7, n = tid & 127;
        avgw[(size_t)(blockIdx.x * 2 + g2) * 128 + n] =
            (csum[0][g2][n] + csum[1][g2][n]) * (1.0f / 16.0f);
    }
}

// ---------------------------------------------------------------- K4: residual + LN2
// Wave-per-row: 4 rows/block, two shfl reductions, no LDS / no syncthreads.
__global__ __launch_bounds__(256) void k4_ln2(const float* __restrict__ x,
                                              const float* __restrict__ w1,
                                              const float* __restrict__ b1,
                                              const unsigned short* __restrict__ attnb,
                                              const float* __restrict__ w2,
                                              const float* __restrict__ b2,
                                              float* __restrict__ out) {
    int lane = threadIdx.x & 63;
    int wave = threadIdx.x >> 6;
    int row  = blockIdx.x * 4 + wave;
    const float4v* xr = (const float4v*)(x + (size_t)row * 1024);
    float4v xv[4];
    float s = 0.f, s2 = 0.f;
    #pragma unroll
    for (int c = 0; c < 4; ++c) {
        xv[c] = xr[c * 64 + lane];
        #pragma unroll
        for (int e = 0; e < 4; ++e) { s += xv[c][e]; s2 += xv[c][e] * xv[c][e]; }
    }
    #pragma unroll
    for (int off = 32; off > 0; off >>= 1) {
        s  += __shfl_xor(s, off, 64);
        s2 += __shfl_xor(s2, off, 64);
    }
    float mean = s * (1.0f / 1024.0f);
    float var  = s2 * (1.0f / 1024.0f) - mean * mean;
    float rs   = rsqrtf(var + LN_EPS);
    float4v r[4];
    s = 0.f; s2 = 0.f;
    #pragma unroll
    for (int c = 0; c < 4; ++c) {
        int idx = c * 64 + lane;
        float4v wv = ((const float4v*)w1)[idx];
        float4v bv = ((const float4v*)b1)[idx];
        short4v av = ((const short4v*)(attnb + (size_t)row * 1024))[idx];
        #pragma unroll
        for (int e = 0; e < 4; ++e) {
            r[c][e] = (xv[c][e] - mean) * rs * wv[e] + bv[e] + bf2f((unsigned short)av[e]);
            s += r[c][e]; s2 += r[c][e] * r[c][e];
        }
    }
    #pragma unroll
    for (int off = 32; off > 0; off >>= 1) {
        s  += __shfl_xor(s, off, 64);
        s2 += __shfl_xor(s2, off, 64);
    }
    float mean2 = s * (1.0f / 1024.0f);
    float var2  = s2 * (1.0f / 1024.0f) - mean2 * mean2;
    float rs2   = rsqrtf(var2 + LN_EPS);
    #pragma unroll
    for (int c = 0; c < 4; ++c) {
        int idx = c * 64 + lane;
        float4v w2v = ((const float4v*)w2)[idx];
        float4v b2v = ((const float4v*)b2)[idx];
        float4v o;
        #pragma unroll
        for (int e = 0; e < 4; ++e)
            o[e] = (r[c][e] - mean2) * rs2 * w2v[e] + b2v[e];
        ((float4v*)(out + (size_t)row * 1024))[idx] = o;
    }
}

// ---------------------------------------------------------------- launch
extern "C" void kernel_launch(void* const* d_in, const int* in_sizes, int n_in,
                              void* d_out, int out_size, void* d_ws, size_t ws_size,
                              hipStream_t stream) {
    const float* x    = (const float*)d_in[0];
    const float* ln1w = (const float*)d_in[1];
    const float* ln1b = (const float*)d_in[2];
    const float* inw  = (const float*)d_in[3];
    const float* inb  = (const float*)d_in[4];
    const float* ln2w = (const float*)d_in[5];
    const float* ln2b = (const float*)d_in[6];
    float* out  = (float*)d_out;
    float* avgw = out + 33554432;           // 256*128*1024

    char* ws = (char*)d_ws;                 // needs ~275 MB
    unsigned short* xnb   = (unsigned short*)(ws);               // K2 input; then Vt
    unsigned short* Vt    = (unsigned short*)(ws);               // K2b output (overlays xnb)
    unsigned short* Qb    = (unsigned short*)(ws + 67108864);
    unsigned short* Kb    = (unsigned short*)(ws + 134217728);
    unsigned short* Vb    = (unsigned short*)(ws + 201326592);
    unsigned short* attnb = (unsigned short*)(ws + 201326592);   // overlays Vb (dead after K2b)
    unsigned short* Wb    = (unsigned short*)(ws + 268435456);

    k0_w_to_bf16<<<1536, 256, 0, stream>>>(inw, Wb);
    k1_ln1<<<8192, 256, 0, stream>>>(x, ln1w, ln1b, xnb);
    k2_qkv_gemm<<<1536, 512, 0, stream>>>(xnb, Wb, inb, Qb, Kb, Vb);
    k2b_vtrans<<<2048, 256, 0, stream>>>(Vb, Vt);
    k3_attn<<<2048, 256, 0, stream>>>(Qb, Kb, Vt, attnb, avgw);
    k4_ln2<<<8192, 256, 0, stream>>>(x, ln1w, ln1b, attnb, ln2w, ln2b, out);
}

// Round 4
// 601.847 us; speedup vs baseline: 1.0506x; 1.0506x over previous
//
#include <hip/hip_runtime.h>

// MultiHeadAttention fused block, MI355X gfx950.
// B=256, NA=128, E=1024, H=16, HD=64. M = B*NA = 32768 rows.
//
// Head-view mapping (fixed by the reshape):  m = i_na*256 + (j>>4),
// e = (j&15)*64 + d  (j = attention group 0..4095, i_na = 0..127 query pos).
//
// Pipeline:
//   K0: in_w fp32 -> bf16                   (Wb)
//   K1: LN1(x) -> bf16                      (xnb), wave-per-row
//   K2: MFMA GEMM xnb @ Wb^T + bias -> GROUP-MAJOR Qg/Kg/Vg [j][i][d]
//       (Qg scaled .125). M-tile = {m = i_na*256 + jq : jq in {2mT,2mT+1}} so
//       each 256-col tile = 8 complete groups -> coalesced 16-KB slab writes.
//       256x256 tile, BK=64, 8-phase counted-vmcnt schedule, swizzled LDS.
//   K3: attention, 1 group/block (128 thr, 2 waves). Dense 16-KB slab reads;
//       V transposed in-register from slab; swapped S'=K Q^T in-wave softmax
//       (verified r3); P panel XOR-swizzled aliasing sQ+sK; 3 barriers.
//       Writes attnb ROW-major (so K4 stays coalesced).
//   K4: recompute LN1 stats, residual + LN2 -> d_out, wave-per-row
//
// Workspace layout (bytes):
//   [0,            67108864)  xnb (K2 input) -> attnb (K3 out)    -- reused
//   [67108864,    134217728)  Qg (group-major)
//   [134217728,   201326592)  Kg
//   [201326592,   268435456)  Vg
//   [268435456,   274726912)  Wb (3072*1024 bf16)
// Total 274.7 MB.

typedef __attribute__((ext_vector_type(4))) float float4v;
typedef __attribute__((ext_vector_type(4))) int   int4v;
typedef __attribute__((ext_vector_type(8))) short short8v;
typedef __attribute__((ext_vector_type(4))) short short4v;

#define LN_EPS 1e-5f

// Direct global->LDS DMA, 16 B per lane. LDS base must be wave-uniform;
// hardware writes base + lane*16.
#define GLL(g, l) __builtin_amdgcn_global_load_lds( \
    (const __attribute__((address_space(1))) unsigned int*)(g), \
    (__attribute__((address_space(3))) unsigned int*)(l), 16, 0, 0)

__device__ __forceinline__ unsigned short f2bf(float f) {
    unsigned int u = __float_as_uint(f);
    u += 0x7FFFu + ((u >> 16) & 1u);   // round-to-nearest-even
    return (unsigned short)(u >> 16);
}
__device__ __forceinline__ float bf2f(unsigned short h) {
    return __uint_as_float(((unsigned int)h) << 16);
}
__device__ __forceinline__ unsigned int pk_bf16(float lo, float hi) {
    unsigned int r;
    asm("v_cvt_pk_bf16_f32 %0, %1, %2" : "=v"(r) : "v"(lo), "v"(hi));
    return r;
}

// ---------------------------------------------------------------- K0: W->bf16
__global__ __launch_bounds__(256) void k0_w_to_bf16(const float* __restrict__ w,
                                                    unsigned short* __restrict__ wb) {
    int idx = blockIdx.x * 256 + threadIdx.x;      // one thread per 8 elems
    const float4v* src = (const float4v*)w;
    float4v a = src[idx * 2];
    float4v b = src[idx * 2 + 1];
    short8v o;
    o[0] = (short)f2bf(a[0]); o[1] = (short)f2bf(a[1]);
    o[2] = (short)f2bf(a[2]); o[3] = (short)f2bf(a[3]);
    o[4] = (short)f2bf(b[0]); o[5] = (short)f2bf(b[1]);
    o[6] = (short)f2bf(b[2]); o[7] = (short)f2bf(b[3]);
    *((short8v*)wb + idx) = o;
}

// ---------------------------------------------------------------- K1: LN1
// Wave-per-row: 4 rows/block, pure shfl reduction, no LDS / no syncthreads.
__global__ __launch_bounds__(256) void k1_ln1(const float* __restrict__ x,
                                              const float* __restrict__ w1,
                                              const float* __restrict__ b1,
                                              unsigned short* __restrict__ xnb) {
    int lane = threadIdx.x & 63;
    int wave = threadIdx.x >> 6;
    int row  = blockIdx.x * 4 + wave;
    const float4v* xr = (const float4v*)(x + (size_t)row * 1024);
    float4v xv[4];
    float s = 0.f, s2 = 0.f;
    #pragma unroll
    for (int c = 0; c < 4; ++c) {
        xv[c] = xr[c * 64 + lane];
        #pragma unroll
        for (int e = 0; e < 4; ++e) { s += xv[c][e]; s2 += xv[c][e] * xv[c][e]; }
    }
    #pragma unroll
    for (int off = 32; off > 0; off >>= 1) {
        s  += __shfl_xor(s, off, 64);
        s2 += __shfl_xor(s2, off, 64);
    }
    float mean = s * (1.0f / 1024.0f);
    float var  = s2 * (1.0f / 1024.0f) - mean * mean;
    float rs   = rsqrtf(var + LN_EPS);
    #pragma unroll
    for (int c = 0; c < 4; ++c) {
        int idx = c * 64 + lane;
        float4v wv = ((const float4v*)w1)[idx];
        float4v bv = ((const float4v*)b1)[idx];
        short4v o;
        #pragma unroll
        for (int e = 0; e < 4; ++e)
            o[e] = (short)f2bf((xv[c][e] - mean) * rs * wv[e] + bv[e]);
        ((short4v*)(xnb + (size_t)row * 1024))[idx] = o;
    }
}

// ---------------------------------------------------------------- K2: QKV GEMM
// C[m][n] = sum_k A[m][k]*W[n][k] + bias[n]; A:32768x1024 bf16, W:3072x1024 bf16.
// M-tile rows r=0..255 map to m = (r&127)*256 + mT*2 + (r>>7)  (fixed jq pair)
// so the output tile = 8 complete groups; epilogue writes 16-KB group slabs.
// 256x256 tile, BK=64, 8 waves (2M x 4N), per-wave 128x64 output (acc[8][4]).
// LDS 128 KiB: sA[2]/sB[2] double-buffered [256][64] bf16 K-tiles, XOR-swizzled
// (linear GLL dest + inverse-swizzled global source). 8 phases/iter, counted
// vmcnt(4) at ph4/ph8 only.
__global__ __launch_bounds__(512, 2) void k2_qkv_gemm(const unsigned short* __restrict__ A,
                                                      const unsigned short* __restrict__ W,
                                                      const float* __restrict__ bias,
                                                      unsigned short* __restrict__ Qg,
                                                      unsigned short* __restrict__ Kg,
                                                      unsigned short* __restrict__ Vg) {
    __shared__ unsigned short smem[65536];           // 128 KiB (also epilogue C-tile)
    unsigned short* sA0 = smem;                      // [256][64] bf16, even K-tile
    unsigned short* sA1 = smem + 16384;              // odd K-tile
    unsigned short* sB0 = smem + 32768;
    unsigned short* sB1 = smem + 49152;

    int bid = blockIdx.x;
    int wg  = (bid & 7) * 192 + (bid >> 3);          // XCD swizzle, 1536 % 8 == 0 (bijective)
    int nT  = wg % 12;                               // N-fastest: 12 consecutive share A panel
    int mT  = wg / 12;                               // jq pair {2mT, 2mT+1}
    int colBase = nT * 256;

    int tid  = threadIdx.x;
    int lane = tid & 63;
    int wave = tid >> 6;
    int wm = wave >> 2, wn = wave & 3;               // 2 x 4 wave grid
    int q4 = lane >> 4, l15 = lane & 15;

    // staging: thread t stages physical LDS bytes [r*8192 + t*16, +16):
    // tile-row = quarter*64 + lrow_s; source colByte = physBy ^ ((row&7)<<4).
    int lrow_s = tid >> 3;                           // row within 64-row quarter
    int srcCol = ((tid & 7) * 16) ^ ((lrow_s & 7) << 4);
    const char* aQ[4];                               // per-quarter A bases (scattered rows)
    #pragma unroll
    for (int q = 0; q < 4; ++q) {
        int trow = q * 64 + lrow_s;
        size_t m = (size_t)(trow & 127) * 256 + (size_t)(mT * 2 + (trow >> 7));
        aQ[q] = (const char*)A + (m << 11) + srcCol;
    }
    const char* wSrc = (const char*)W + ((size_t)(colBase + lrow_s) << 11) + srcCol;
    int waveOff = wave * 1024;

    // fragment read offsets (bytes): row*128 + ((kk*64 + q4*16) ^ ((l15&7)<<4))
    int xorv = (l15 & 7) << 4;
    int aRow = (wm * 128 + l15) * 128;
    int bRow = (wn * 64 + l15) * 128;
    int bc0 = (q4 * 16) ^ xorv;                      // kk = 0
    int bc1 = (64 + q4 * 16) ^ xorv;                 // kk = 1

    float bv[4];
    #pragma unroll
    for (int n = 0; n < 4; ++n) bv[n] = bias[colBase + wn * 64 + n * 16 + l15];

    float4v acc[8][4];
    #pragma unroll
    for (int t = 0; t < 8; ++t)
        #pragma unroll
        for (int n = 0; n < 4; ++n) acc[t][n] = (float4v){0.f, 0.f, 0.f, 0.f};

#define STAGE_A(lds, ktB_, h) do { \
    GLL(aQ[2*(h)]   + (ktB_), (char*)(lds) + (2*(h))   * 8192 + waveOff); \
    GLL(aQ[2*(h)+1] + (ktB_), (char*)(lds) + (2*(h)+1) * 8192 + waveOff); \
} while (0)
#define STAGE_W(lds, ktB_, h) do { \
    GLL(wSrc + (ktB_) + (2*(h))   * 131072, (char*)(lds) + (2*(h))   * 8192 + waveOff); \
    GLL(wSrc + (ktB_) + (2*(h)+1) * 131072, (char*)(lds) + (2*(h)+1) * 8192 + waveOff); \
} while (0)
#define LDB(SB) do { \
    const char* c_ = (const char*)(SB); \
    _Pragma("unroll") \
    for (int n = 0; n < 4; ++n) { \
        bf[n][0] = *(const short8v*)(c_ + bRow + n * 2048 + bc0); \
        bf[n][1] = *(const short8v*)(c_ + bRow + n * 2048 + bc1); \
    } \
} while (0)
#define LDA2(SA, T0_) do { \
    const char* c_ = (const char*)(SA); \
    af[0][0] = *(const short8v*)(c_ + aRow + (T0_)     * 2048 + bc0); \
    af[0][1] = *(const short8v*)(c_ + aRow + (T0_)     * 2048 + bc1); \
    af[1][0] = *(const short8v*)(c_ + aRow + (T0_ + 1) * 2048 + bc0); \
    af[1][1] = *(const short8v*)(c_ + aRow + (T0_ + 1) * 2048 + bc1); \
} while (0)
#define MFMA8(T0_) do { \
    __builtin_amdgcn_s_setprio(1); \
    _Pragma("unroll") \
    for (int n = 0; n < 4; ++n) { \
        acc[T0_][n]     = __builtin_amdgcn_mfma_f32_16x16x32_bf16(af[0][0], bf[n][0], acc[T0_][n], 0, 0, 0); \
        acc[T0_][n]     = __builtin_amdgcn_mfma_f32_16x16x32_bf16(af[0][1], bf[n][1], acc[T0_][n], 0, 0, 0); \
        acc[T0_ + 1][n] = __builtin_amdgcn_mfma_f32_16x16x32_bf16(af[1][0], bf[n][0], acc[T0_ + 1][n], 0, 0, 0); \
        acc[T0_ + 1][n] = __builtin_amdgcn_mfma_f32_16x16x32_bf16(af[1][1], bf[n][1], acc[T0_ + 1][n], 0, 0, 0); \
    } \
    __builtin_amdgcn_s_setprio(0); \
} while (0)
#define PH_SYNC do { __builtin_amdgcn_s_barrier(); asm volatile("s_waitcnt lgkmcnt(0)"); } while (0)
#define PH_END  __builtin_amdgcn_s_barrier()

    // prologue: T0 full (A+B) + T1.B; leave T1.B (4 loads) in flight
    STAGE_A(sA0, 0, 0);
    STAGE_A(sA0, 0, 1);
    STAGE_W(sB0, 0, 0);
    STAGE_W(sB0, 0, 1);
    STAGE_W(sB1, 128, 0);
    STAGE_W(sB1, 128, 1);
    asm volatile("s_waitcnt vmcnt(4)");
    __builtin_amdgcn_s_barrier();

    short8v af[2][2], bf[4][2];

    #pragma unroll 1
    for (int i = 0; i < 8; ++i) {
        int ktB = i << 8;                 // byte K-offset of T(2i) (tile = 128 B)
        bool nl = (i < 7);
        // PH1: T(2i) quad0 from buf0; stage T(2i+1).A0 -> buf1
        LDB(sB0); LDA2(sA0, 0);
        STAGE_A(sA1, ktB + 128, 0);
        PH_SYNC; MFMA8(0); PH_END;
        // PH2: quad1; stage T(2i+1).A1
        LDA2(sA0, 2);
        STAGE_A(sA1, ktB + 128, 1);
        PH_SYNC; MFMA8(2); PH_END;
        // PH3: quad2; stage T(2i+2).B0
        LDA2(sA0, 4);
        if (nl) STAGE_W(sB0, ktB + 256, 0);
        PH_SYNC; MFMA8(4); PH_END;
        // PH4: quad3; stage T(2i+2).B1; counted wait -> T(2i+1) fully landed
        LDA2(sA0, 6);
        if (nl) { STAGE_W(sB0, ktB + 256, 1); asm volatile("s_waitcnt vmcnt(4)"); }
        else    { asm volatile("s_waitcnt vmcnt(0)"); }
        PH_SYNC; MFMA8(6); PH_END;
        // PH5: T(2i+1) quad0 from buf1; stage T(2i+2).A0
        LDB(sB1); LDA2(sA1, 0);
        if (nl) STAGE_A(sA0, ktB + 256, 0);
        PH_SYNC; MFMA8(0); PH_END;
        // PH6: quad1; stage T(2i+2).A1
        LDA2(sA1, 2);
        if (nl) STAGE_A(sA0, ktB + 256, 1);
        PH_SYNC; MFMA8(2); PH_END;
        // PH7: quad2; stage T(2i+3).B0
        LDA2(sA1, 4);
        if (nl) STAGE_W(sB1, ktB + 384, 0);
        PH_SYNC; MFMA8(4); PH_END;
        // PH8: quad3; stage T(2i+3).B1; counted wait -> T(2i+2) fully landed
        LDA2(sA1, 6);
        if (nl) { STAGE_W(sB1, ktB + 384, 1); asm volatile("s_waitcnt vmcnt(4)"); }
        PH_SYNC; MFMA8(6); PH_END;
    }
#undef STAGE_A
#undef STAGE_W
#undef LDB
#undef LDA2
#undef MFMA8
#undef PH_SYNC
#undef PH_END

    // Epilogue: bias+scale into XOR-swizzled LDS C-tile, then stream 8
    // group-major 16-KB slabs (wave w -> group slab w), fully coalesced.
    __syncthreads();
    float scale = (colBase < 1024) ? 0.125f : 1.0f;
    unsigned short* outb = (colBase < 1024) ? Qg : (colBase < 2048) ? Kg : Vg;
    #pragma unroll
    for (int t = 0; t < 8; ++t)
        #pragma unroll
        for (int n = 0; n < 4; ++n)
            #pragma unroll
            for (int g = 0; g < 4; ++g) {
                int row  = wm * 128 + t * 16 + q4 * 4 + g;
                int colb = (wn * 64 + n * 16 + l15) * 2;
                *(unsigned short*)((char*)smem + row * 512 + (colb ^ ((row & 7) << 4))) =
                    f2bf((acc[t][n][g] + bv[n]) * scale);
            }
    __syncthreads();
    {
        int rr = wave >> 2, c = wave & 3;            // slab = (jq half, col band)
        int jg = (mT * 2 + rr) * 16 + ((colBase & 1023) >> 6) + c;
        unsigned short* dstG = outb + (size_t)jg * 8192 + (lane & 7) * 8;
        #pragma unroll
        for (int it = 0; it < 16; ++it) {
            int i_na = it * 8 + (lane >> 3);
            int r = rr * 128 + i_na;
            int colb = (c * 128 + (lane & 7) * 16) ^ ((r & 7) << 4);
            short8v v = *(const short8v*)((const char*)smem + r * 512 + colb);
            *(short8v*)(dstG + (size_t)i_na * 64) = v;
        }
    }
}

// ---------------------------------------------------------------- K3: attention
// 4096 blocks (1 group), 128 threads (2 waves); wave wm owns query rows
// m in [wm*64, wm*64+64) x all 128 keys. All inputs are dense 16-KB slabs.
// LDS 51.2 KB (3 blocks/CU): sQ[16K] sK[16K] sVt[17408] csum[1K];
// P panel [128][256B] XOR-swizzled aliases sQ+sK after barrier 2.
__global__ __launch_bounds__(128) void k3_attn(const unsigned short* __restrict__ Qg,
                                               const unsigned short* __restrict__ Kg,
                                               const unsigned short* __restrict__ Vg,
                                               unsigned short* __restrict__ attnb,
                                               float* __restrict__ avgw) {
    __shared__ __attribute__((aligned(128))) char smem[51200];
    float* csum = (float*)(smem + 50176);            // [2][128]

    int j = blockIdx.x;
    int tid = threadIdx.x;
    int lane = tid & 63;
    int wm = tid >> 6;                               // wave = query half
    int q4 = lane >> 4, l15 = lane & 15;

    // Stage Q,K slabs via GLL: linear LDS dest, source col XOR-pre-swizzled
    // within the 128-B slab row (row&7 == lane>>3 within each 8-row GLL).
    {
        const char* qg = (const char*)(Qg + (size_t)j * 8192);
        const char* kg = (const char*)(Kg + (size_t)j * 8192);
        int swz = ((lane & 7) ^ (lane >> 3)) << 4;
        #pragma unroll
        for (int blk = 0; blk < 8; ++blk) {
            int row0 = wm * 64 + blk * 8;
            int src = (row0 + (lane >> 3)) * 128 + swz;
            GLL(qg + src, smem + row0 * 128);
            GLL(kg + src, smem + 16384 + row0 * 128);
        }
    }
    // V: in-register 8x8 transpose from dense slab -> sVt[64 d][272 B rows].
    {
        int nb = tid & 15, db = tid >> 4;            // db in [0,8)
        const unsigned short* vsrc = Vg + (size_t)j * 8192 + (nb * 8) * 64 + db * 8;
        short8v in[8];
        #pragma unroll
        for (int k = 0; k < 8; ++k) in[k] = *(const short8v*)(vsrc + k * 64);
        char* vt = smem + 32768;
        #pragma unroll
        for (int c = 0; c < 8; ++c) {
            short8v o;
            #pragma unroll
            for (int k = 0; k < 8; ++k) o[k] = in[k][c];
            *(short8v*)(vt + (db * 8 + c) * 272 + nb * 16) = o;
        }
    }
    __syncthreads();                                 // barrier 1

    // S'[n][m] = K Q^T: per-lane n = tn*16+q4*4+g, m = tm*16+l15 (+wm*64).
    float4v S[8][4];
    #pragma unroll
    for (int a = 0; a < 8; ++a)
        #pragma unroll
        for (int b = 0; b < 4; ++b) S[a][b] = (float4v){0.f, 0.f, 0.f, 0.f};
    #pragma unroll
    for (int ks = 0; ks < 2; ++ks) {
        int cb = (ks * 64 + q4 * 16) ^ ((l15 & 7) << 4);
        short8v qf[4];
        #pragma unroll
        for (int tm = 0; tm < 4; ++tm)
            qf[tm] = *(const short8v*)(smem + (wm * 64 + tm * 16 + l15) * 128 + cb);
        #pragma unroll
        for (int tn = 0; tn < 8; ++tn) {
            short8v kf = *(const short8v*)(smem + 16384 + (tn * 16 + l15) * 128 + cb);
            #pragma unroll
            for (int tm = 0; tm < 4; ++tm)
                S[tn][tm] = __builtin_amdgcn_mfma_f32_16x16x32_bf16(kf, qf[tm], S[tn][tm], 0, 0, 0);
        }
    }

    // In-wave softmax over keys n: in-lane reduce + shfl_xor(16,32) across q4.
    float rmax[4], inv[4];
    #pragma unroll
    for (int tm = 0; tm < 4; ++tm) {
        float m0 = S[0][tm][0];
        #pragma unroll
        for (int tn = 0; tn < 8; ++tn)
            #pragma unroll
            for (int g = 0; g < 4; ++g) m0 = fmaxf(m0, S[tn][tm][g]);
        m0 = fmaxf(m0, __shfl_xor(m0, 16, 64));
        m0 = fmaxf(m0, __shfl_xor(m0, 32, 64));
        rmax[tm] = m0;
    }
    #pragma unroll
    for (int tm = 0; tm < 4; ++tm) {
        float t0 = 0.f;
        #pragma unroll
        for (int tn = 0; tn < 8; ++tn)
            #pragma unroll
            for (int g = 0; g < 4; ++g) {
                float e = __expf(S[tn][tm][g] - rmax[tm]);
                S[tn][tm][g] = e;
                t0 += e;
            }
        t0 += __shfl_xor(t0, 16, 64);
        t0 += __shfl_xor(t0, 32, 64);
        inv[tm] = 1.0f / t0;
    }
    #pragma unroll
    for (int tn = 0; tn < 8; ++tn)
        #pragma unroll
        for (int tm = 0; tm < 4; ++tm)
            #pragma unroll
            for (int g = 0; g < 4; ++g) S[tn][tm][g] *= inv[tm];

    // avg_w partials: sum over m = in-lane over tm + shfl_xor(1,2,4,8) over l15.
    #pragma unroll
    for (int tn = 0; tn < 8; ++tn) {
        #pragma unroll
        for (int g = 0; g < 4; ++g) {
            float cs = S[tn][0][g] + S[tn][1][g] + S[tn][2][g] + S[tn][3][g];
            cs += __shfl_xor(cs, 1, 64);
            cs += __shfl_xor(cs, 2, 64);
            cs += __shfl_xor(cs, 4, 64);
            cs += __shfl_xor(cs, 8, 64);
            if (l15 == 0) csum[wm * 128 + tn * 16 + q4 * 4 + g] = cs;
        }
    }
    __syncthreads();                                 // barrier 2: sQ/sK reads done

    // P -> [128][256B] XOR-swizzled panel aliasing sQ+sK (wave-disjoint rows).
    char* sP = smem;
    #pragma unroll
    for (int tn = 0; tn < 8; ++tn)
        #pragma unroll
        for (int tm = 0; tm < 4; ++tm) {
            int row = wm * 64 + tm * 16 + l15;
            int swz = (row & 7) << 4;
            #pragma unroll
            for (int p = 0; p < 2; ++p) {
                unsigned int pk = pk_bf16(S[tn][tm][2 * p], S[tn][tm][2 * p + 1]);
                int x = ((tn * 16 + q4 * 4 + 2 * p) * 2) ^ swz;
                *(unsigned int*)(sP + row * 256 + x) = pk;
            }
        }

    // PV: O[m][d] = sum_n P[m][n] V^T[d][n]; pf from own P rows, vf from sVt.
    float4v O[4][4];
    #pragma unroll
    for (int a = 0; a < 4; ++a)
        #pragma unroll
        for (int b = 0; b < 4; ++b) O[a][b] = (float4v){0.f, 0.f, 0.f, 0.f};
    const char* vt = smem + 32768;
    #pragma unroll
    for (int ks = 0; ks < 4; ++ks) {
        int nB = (ks * 32 + q4 * 8) * 2;             // byte offset of n-chunk
        short8v pf[4], vf[4];
        #pragma unroll
        for (int t = 0; t < 4; ++t)
            vf[t] = *(const short8v*)(vt + (t * 16 + l15) * 272 + nB);
        #pragma unroll
        for (int tm = 0; tm < 4; ++tm) {
            int row = wm * 64 + tm * 16 + l15;
            pf[tm] = *(const short8v*)(sP + row * 256 + (nB ^ ((row & 7) << 4)));
        }
        #pragma unroll
        for (int tm = 0; tm < 4; ++tm)
            #pragma unroll
            for (int tno = 0; tno < 4; ++tno)
                O[tm][tno] = __builtin_amdgcn_mfma_f32_16x16x32_bf16(pf[tm], vf[tno], O[tm][tno], 0, 0, 0);
    }

    // Store O row-major: row m = i_na*256 + (j>>4), cols (j&15)*64 + d.
    {
        int jq = j >> 4;
        int eb = (j & 15) * 64;
        #pragma unroll
        for (int tm = 0; tm < 4; ++tm)
            #pragma unroll
            for (int g = 0; g < 4; ++g) {
                int i_na = wm * 64 + tm * 16 + q4 * 4 + g;
                size_t mrow = (size_t)i_na * 256 + jq;
                #pragma unroll
                for (int tno = 0; tno < 4; ++tno)
                    attnb[mrow * 1024 + eb + tno * 16 + l15] = f2bf(O[tm][tno][g]);
            }
    }

    __syncthreads();                                 // barrier 3: csum combine
    avgw[(size_t)j * 128 + tid] = (csum[tid] + csum[128 + tid]) * (1.0f / 16.0f);
}

// ---------------------------------------------------------------- K4: residual + LN2
// Wave-per-row: 4 rows/block, two shfl reductions, no LDS / no syncthreads.
__global__ __launch_bounds__(256) void k4_ln2(const float* __restrict__ x,
                                              const float* __restrict__ w1,
                                              const float* __restrict__ b1,
                                              const unsigned short* __restrict__ attnb,
                                              const float* __restrict__ w2,
                                              const float* __restrict__ b2,
                                              float* __restrict__ out) {
    int lane = threadIdx.x & 63;
    int wave = threadIdx.x >> 6;
    int row  = blockIdx.x * 4 + wave;
    const float4v* xr = (const float4v*)(x + (size_t)row * 1024);
    float4v xv[4];
    float s = 0.f, s2 = 0.f;
    #pragma unroll
    for (int c = 0; c < 4; ++c) {
        xv[c] = xr[c * 64 + lane];
        #pragma unroll
        for (int e = 0; e < 4; ++e) { s += xv[c][e]; s2 += xv[c][e] * xv[c][e]; }
    }
    #pragma unroll
    for (int off = 32; off > 0; off >>= 1) {
        s  += __shfl_xor(s, off, 64);
        s2 += __shfl_xor(s2, off, 64);
    }
    float mean = s * (1.0f / 1024.0f);
    float var  = s2 * (1.0f / 1024.0f) - mean * mean;
    float rs   = rsqrtf(var + LN_EPS);
    float4v r[4];
    s = 0.f; s2 = 0.f;
    #pragma unroll
    for (int c = 0; c < 4; ++c) {
        int idx = c * 64 + lane;
        float4v wv = ((const float4v*)w1)[idx];
        float4v bv = ((const float4v*)b1)[idx];
        short4v av = ((const short4v*)(attnb + (size_t)row * 1024))[idx];
        #pragma unroll
        for (int e = 0; e < 4; ++e) {
            r[c][e] = (xv[c][e] - mean) * rs * wv[e] + bv[e] + bf2f((unsigned short)av[e]);
            s += r[c][e]; s2 += r[c][e] * r[c][e];
        }
    }
    #pragma unroll
    for (int off = 32; off > 0; off >>= 1) {
        s  += __shfl_xor(s, off, 64);
        s2 += __shfl_xor(s2, off, 64);
    }
    float mean2 = s * (1.0f / 1024.0f);
    float var2  = s2 * (1.0f / 1024.0f) - mean2 * mean2;
    float rs2   = rsqrtf(var2 + LN_EPS);
    #pragma unroll
    for (int c = 0; c < 4; ++c) {
        int idx = c * 64 + lane;
        float4v w2v = ((const float4v*)w2)[idx];
        float4v b2v = ((const float4v*)b2)[idx];
        float4v o;
        #pragma unroll
        for (int e = 0; e < 4; ++e)
            o[e] = (r[c][e] - mean2) * rs2 * w2v[e] + b2v[e];
        ((float4v*)(out + (size_t)row * 1024))[idx] = o;
    }
}

// ---------------------------------------------------------------- launch
extern "C" void kernel_launch(void* const* d_in, const int* in_sizes, int n_in,
                              void* d_out, int out_size, void* d_ws, size_t ws_size,
                              hipStream_t stream) {
    const float* x    = (const float*)d_in[0];
    const float* ln1w = (const float*)d_in[1];
    const float* ln1b = (const float*)d_in[2];
    const float* inw  = (const float*)d_in[3];
    const float* inb  = (const float*)d_in[4];
    const float* ln2w = (const float*)d_in[5];
    const float* ln2b = (const float*)d_in[6];
    float* out  = (float*)d_out;
    float* avgw = out + 33554432;           // 256*128*1024

    char* ws = (char*)d_ws;                 // needs ~275 MB
    unsigned short* xnb   = (unsigned short*)(ws);               // K2 input; then attnb
    unsigned short* attnb = (unsigned short*)(ws);               // overlays xnb (dead after K2)
    unsigned short* Qg    = (unsigned short*)(ws + 67108864);
    unsigned short* Kg    = (unsigned short*)(ws + 134217728);
    unsigned short* Vg    = (unsigned short*)(ws + 201326592);
    unsigned short* Wb    = (unsigned short*)(ws + 268435456);

    k0_w_to_bf16<<<1536, 256, 0, stream>>>(inw, Wb);
    k1_ln1<<<8192, 256, 0, stream>>>(x, ln1w, ln1b, xnb);
    k2_qkv_gemm<<<1536, 512, 0, stream>>>(xnb, Wb, inb, Qg, Kg, Vg);
    k3_attn<<<4096, 128, 0, stream>>>(Qg, Kg, Vg, attnb, avgw);
    k4_ln2<<<8192, 256, 0, stream>>>(x, ln1w, ln1b, attnb, ln2w, ln2b, out);
}

// Round 5
// 598.362 us; speedup vs baseline: 1.0567x; 1.0058x over previous
//
#include <hip/hip_runtime.h>

// MultiHeadAttention fused block, MI355X gfx950.
// B=256, NA=128, E=1024, H=16, HD=64. M = B*NA = 32768 rows.
//
// Head-view mapping (fixed by the reshape):  m = i_na*256 + (j>>4),
// e = (j&15)*64 + d  (j = attention group 0..4095, i_na = 0..127 query pos).
//
// Pipeline:
//   K0: in_w fp32 -> bf16                   (Wb)
//   K1: LN1(x) -> bf16                      (xnb), block-per-row (r0 version)
//   K2: MFMA GEMM xnb @ Wb^T + bias -> GROUP-MAJOR Qg/Kg/Vg [j][i][d]
//       (Qg scaled .125). M-tile = {m = i_na*256 + jq : jq in {2mT,2mT+1}} so
//       each 256-col tile = 8 complete groups -> coalesced 16-KB slab writes.
//       256x256 tile, BK=64, 8-phase counted-vmcnt schedule, swizzled LDS.
//   K3: attention, 1 group/block (128 thr, 2 waves). Dense 16-KB slab reads;
//       V transposed in-register from slab; swapped S'=K Q^T in-wave softmax;
//       P panel XOR-swizzled aliasing sQ+sK; 3 barriers. Row-major attnb out.
//   K4: recompute LN1 stats, residual + LN2 -> d_out, block-per-row (r0 ver.)
//
// Workspace layout (bytes):
//   [0,            67108864)  xnb (K2 input) -> attnb (K3 out)    -- reused
//   [67108864,    134217728)  Qg (group-major)
//   [134217728,   201326592)  Kg
//   [201326592,   268435456)  Vg
//   [268435456,   274726912)  Wb (3072*1024 bf16)
// Total 274.7 MB.

typedef __attribute__((ext_vector_type(4))) float float4v;
typedef __attribute__((ext_vector_type(4))) int   int4v;
typedef __attribute__((ext_vector_type(8))) short short8v;
typedef __attribute__((ext_vector_type(4))) short short4v;

#define LN_EPS 1e-5f

// Direct global->LDS DMA, 16 B per lane. LDS base must be wave-uniform;
// hardware writes base + lane*16.
#define GLL(g, l) __builtin_amdgcn_global_load_lds( \
    (const __attribute__((address_space(1))) unsigned int*)(g), \
    (__attribute__((address_space(3))) unsigned int*)(l), 16, 0, 0)

__device__ __forceinline__ unsigned short f2bf(float f) {
    unsigned int u = __float_as_uint(f);
    u += 0x7FFFu + ((u >> 16) & 1u);   // round-to-nearest-even
    return (unsigned short)(u >> 16);
}
__device__ __forceinline__ float bf2f(unsigned short h) {
    return __uint_as_float(((unsigned int)h) << 16);
}
__device__ __forceinline__ unsigned int pk_bf16(float lo, float hi) {
    unsigned int r;
    asm("v_cvt_pk_bf16_f32 %0, %1, %2" : "=v"(r) : "v"(lo), "v"(hi));
    return r;
}

// ---------------------------------------------------------------- K0: W->bf16
__global__ __launch_bounds__(256) void k0_w_to_bf16(const float* __restrict__ w,
                                                    unsigned short* __restrict__ wb) {
    int idx = blockIdx.x * 256 + threadIdx.x;      // one thread per 8 elems
    const float4v* src = (const float4v*)w;
    float4v a = src[idx * 2];
    float4v b = src[idx * 2 + 1];
    short8v o;
    o[0] = (short)f2bf(a[0]); o[1] = (short)f2bf(a[1]);
    o[2] = (short)f2bf(a[2]); o[3] = (short)f2bf(a[3]);
    o[4] = (short)f2bf(b[0]); o[5] = (short)f2bf(b[1]);
    o[6] = (short)f2bf(b[2]); o[7] = (short)f2bf(b[3]);
    *((short8v*)wb + idx) = o;
}

// --------------------------------------------------------- block reduction
__device__ __forceinline__ void block_reduce_2(float& s, float& s2, float* red) {
    #pragma unroll
    for (int off = 32; off > 0; off >>= 1) {
        s  += __shfl_xor(s, off, 64);
        s2 += __shfl_xor(s2, off, 64);
    }
    __syncthreads();                      // also protects re-use of red
    if ((threadIdx.x & 63) == 0) {
        red[(threadIdx.x >> 6) * 2]     = s;
        red[(threadIdx.x >> 6) * 2 + 1] = s2;
    }
    __syncthreads();
    s  = red[0] + red[2] + red[4] + red[6];
    s2 = red[1] + red[3] + red[5] + red[7];
}

// ---------------------------------------------------------------- K1: LN1
__global__ __launch_bounds__(256) void k1_ln1(const float* __restrict__ x,
                                              const float* __restrict__ w1,
                                              const float* __restrict__ b1,
                                              unsigned short* __restrict__ xnb) {
    __shared__ float red[8];
    int row = blockIdx.x;
    int tid = threadIdx.x;
    float4v xv = ((const float4v*)(x + (size_t)row * 1024))[tid];
    float s  = xv[0] + xv[1] + xv[2] + xv[3];
    float s2 = xv[0]*xv[0] + xv[1]*xv[1] + xv[2]*xv[2] + xv[3]*xv[3];
    block_reduce_2(s, s2, red);
    float mean = s * (1.0f / 1024.0f);
    float var  = s2 * (1.0f / 1024.0f) - mean * mean;
    float rs   = rsqrtf(var + LN_EPS);
    float4v wv = ((const float4v*)w1)[tid];
    float4v bv = ((const float4v*)b1)[tid];
    short4v o;
    #pragma unroll
    for (int c = 0; c < 4; ++c)
        o[c] = (short)f2bf((xv[c] - mean) * rs * wv[c] + bv[c]);
    ((short4v*)(xnb + (size_t)row * 1024))[tid] = o;
}

// ---------------------------------------------------------------- K2: QKV GEMM
// C[m][n] = sum_k A[m][k]*W[n][k] + bias[n]; A:32768x1024 bf16, W:3072x1024 bf16.
// M-tile rows r=0..255 map to m = (r&127)*256 + mT*2 + (r>>7)  (fixed jq pair)
// so the output tile = 8 complete groups; epilogue writes 16-KB group slabs.
// 256x256 tile, BK=64, 8 waves (2M x 4N), per-wave 128x64 output (acc[8][4]).
// LDS 128 KiB: sA[2]/sB[2] double-buffered [256][64] bf16 K-tiles, XOR-swizzled
// (linear GLL dest + inverse-swizzled global source). 8 phases/iter, counted
// vmcnt(4) at ph4/ph8 only.
__global__ __launch_bounds__(512, 2) void k2_qkv_gemm(const unsigned short* __restrict__ A,
                                                      const unsigned short* __restrict__ W,
                                                      const float* __restrict__ bias,
                                                      unsigned short* __restrict__ Qg,
                                                      unsigned short* __restrict__ Kg,
                                                      unsigned short* __restrict__ Vg) {
    __shared__ unsigned short smem[65536];           // 128 KiB (also epilogue C-tile)
    unsigned short* sA0 = smem;                      // [256][64] bf16, even K-tile
    unsigned short* sA1 = smem + 16384;              // odd K-tile
    unsigned short* sB0 = smem + 32768;
    unsigned short* sB1 = smem + 49152;

    int bid = blockIdx.x;
    int wg  = (bid & 7) * 192 + (bid >> 3);          // XCD swizzle, 1536 % 8 == 0 (bijective)
    int nT  = wg % 12;                               // N-fastest: 12 consecutive share A panel
    int mT  = wg / 12;                               // jq pair {2mT, 2mT+1}
    int colBase = nT * 256;

    int tid  = threadIdx.x;
    int lane = tid & 63;
    int wave = tid >> 6;
    int wm = wave >> 2, wn = wave & 3;               // 2 x 4 wave grid
    int q4 = lane >> 4, l15 = lane & 15;

    // staging: thread t stages physical LDS bytes [r*8192 + t*16, +16):
    // tile-row = quarter*64 + lrow_s; source colByte = physBy ^ ((row&7)<<4).
    int lrow_s = tid >> 3;                           // row within 64-row quarter
    int srcCol = ((tid & 7) * 16) ^ ((lrow_s & 7) << 4);
    const char* aQ[4];                               // per-quarter A bases (scattered rows)
    #pragma unroll
    for (int q = 0; q < 4; ++q) {
        int trow = q * 64 + lrow_s;
        size_t m = (size_t)(trow & 127) * 256 + (size_t)(mT * 2 + (trow >> 7));
        aQ[q] = (const char*)A + (m << 11) + srcCol;
    }
    const char* wSrc = (const char*)W + ((size_t)(colBase + lrow_s) << 11) + srcCol;
    int waveOff = wave * 1024;

    // fragment read offsets (bytes): row*128 + ((kk*64 + q4*16) ^ ((l15&7)<<4))
    int xorv = (l15 & 7) << 4;
    int aRow = (wm * 128 + l15) * 128;
    int bRow = (wn * 64 + l15) * 128;
    int bc0 = (q4 * 16) ^ xorv;                      // kk = 0
    int bc1 = (64 + q4 * 16) ^ xorv;                 // kk = 1

    float bv[4];
    #pragma unroll
    for (int n = 0; n < 4; ++n) bv[n] = bias[colBase + wn * 64 + n * 16 + l15];

    float4v acc[8][4];
    #pragma unroll
    for (int t = 0; t < 8; ++t)
        #pragma unroll
        for (int n = 0; n < 4; ++n) acc[t][n] = (float4v){0.f, 0.f, 0.f, 0.f};

#define STAGE_A(lds, ktB_, h) do { \
    GLL(aQ[2*(h)]   + (ktB_), (char*)(lds) + (2*(h))   * 8192 + waveOff); \
    GLL(aQ[2*(h)+1] + (ktB_), (char*)(lds) + (2*(h)+1) * 8192 + waveOff); \
} while (0)
#define STAGE_W(lds, ktB_, h) do { \
    GLL(wSrc + (ktB_) + (2*(h))   * 131072, (char*)(lds) + (2*(h))   * 8192 + waveOff); \
    GLL(wSrc + (ktB_) + (2*(h)+1) * 131072, (char*)(lds) + (2*(h)+1) * 8192 + waveOff); \
} while (0)
#define LDB(SB) do { \
    const char* c_ = (const char*)(SB); \
    _Pragma("unroll") \
    for (int n = 0; n < 4; ++n) { \
        bf[n][0] = *(const short8v*)(c_ + bRow + n * 2048 + bc0); \
        bf[n][1] = *(const short8v*)(c_ + bRow + n * 2048 + bc1); \
    } \
} while (0)
#define LDA2(SA, T0_) do { \
    const char* c_ = (const char*)(SA); \
    af[0][0] = *(const short8v*)(c_ + aRow + (T0_)     * 2048 + bc0); \
    af[0][1] = *(const short8v*)(c_ + aRow + (T0_)     * 2048 + bc1); \
    af[1][0] = *(const short8v*)(c_ + aRow + (T0_ + 1) * 2048 + bc0); \
    af[1][1] = *(const short8v*)(c_ + aRow + (T0_ + 1) * 2048 + bc1); \
} while (0)
#define MFMA8(T0_) do { \
    __builtin_amdgcn_s_setprio(1); \
    _Pragma("unroll") \
    for (int n = 0; n < 4; ++n) { \
        acc[T0_][n]     = __builtin_amdgcn_mfma_f32_16x16x32_bf16(af[0][0], bf[n][0], acc[T0_][n], 0, 0, 0); \
        acc[T0_][n]     = __builtin_amdgcn_mfma_f32_16x16x32_bf16(af[0][1], bf[n][1], acc[T0_][n], 0, 0, 0); \
        acc[T0_ + 1][n] = __builtin_amdgcn_mfma_f32_16x16x32_bf16(af[1][0], bf[n][0], acc[T0_ + 1][n], 0, 0, 0); \
        acc[T0_ + 1][n] = __builtin_amdgcn_mfma_f32_16x16x32_bf16(af[1][1], bf[n][1], acc[T0_ + 1][n], 0, 0, 0); \
    } \
    __builtin_amdgcn_s_setprio(0); \
} while (0)
#define PH_SYNC do { __builtin_amdgcn_s_barrier(); asm volatile("s_waitcnt lgkmcnt(0)"); } while (0)
#define PH_END  __builtin_amdgcn_s_barrier()

    // prologue: T0 full (A+B) + T1.B; leave T1.B (4 loads) in flight
    STAGE_A(sA0, 0, 0);
    STAGE_A(sA0, 0, 1);
    STAGE_W(sB0, 0, 0);
    STAGE_W(sB0, 0, 1);
    STAGE_W(sB1, 128, 0);
    STAGE_W(sB1, 128, 1);
    asm volatile("s_waitcnt vmcnt(4)");
    __builtin_amdgcn_s_barrier();

    short8v af[2][2], bf[4][2];

    #pragma unroll 1
    for (int i = 0; i < 8; ++i) {
        int ktB = i << 8;                 // byte K-offset of T(2i) (tile = 128 B)
        bool nl = (i < 7);
        // PH1: T(2i) quad0 from buf0; stage T(2i+1).A0 -> buf1
        LDB(sB0); LDA2(sA0, 0);
        STAGE_A(sA1, ktB + 128, 0);
        PH_SYNC; MFMA8(0); PH_END;
        // PH2: quad1; stage T(2i+1).A1
        LDA2(sA0, 2);
        STAGE_A(sA1, ktB + 128, 1);
        PH_SYNC; MFMA8(2); PH_END;
        // PH3: quad2; stage T(2i+2).B0
        LDA2(sA0, 4);
        if (nl) STAGE_W(sB0, ktB + 256, 0);
        PH_SYNC; MFMA8(4); PH_END;
        // PH4: quad3; stage T(2i+2).B1; counted wait -> T(2i+1) fully landed
        LDA2(sA0, 6);
        if (nl) { STAGE_W(sB0, ktB + 256, 1); asm volatile("s_waitcnt vmcnt(4)"); }
        else    { asm volatile("s_waitcnt vmcnt(0)"); }
        PH_SYNC; MFMA8(6); PH_END;
        // PH5: T(2i+1) quad0 from buf1; stage T(2i+2).A0
        LDB(sB1); LDA2(sA1, 0);
        if (nl) STAGE_A(sA0, ktB + 256, 0);
        PH_SYNC; MFMA8(0); PH_END;
        // PH6: quad1; stage T(2i+2).A1
        LDA2(sA1, 2);
        if (nl) STAGE_A(sA0, ktB + 256, 1);
        PH_SYNC; MFMA8(2); PH_END;
        // PH7: quad2; stage T(2i+3).B0
        LDA2(sA1, 4);
        if (nl) STAGE_W(sB1, ktB + 384, 0);
        PH_SYNC; MFMA8(4); PH_END;
        // PH8: quad3; stage T(2i+3).B1; counted wait -> T(2i+2) fully landed
        LDA2(sA1, 6);
        if (nl) { STAGE_W(sB1, ktB + 384, 1); asm volatile("s_waitcnt vmcnt(4)"); }
        PH_SYNC; MFMA8(6); PH_END;
    }
#undef STAGE_A
#undef STAGE_W
#undef LDB
#undef LDA2
#undef MFMA8
#undef PH_SYNC
#undef PH_END

    // Epilogue: bias+scale into XOR-swizzled LDS C-tile, then stream 8
    // group-major 16-KB slabs (wave w -> group slab w), fully coalesced.
    __syncthreads();
    float scale = (colBase < 1024) ? 0.125f : 1.0f;
    unsigned short* outb = (colBase < 1024) ? Qg : (colBase < 2048) ? Kg : Vg;
    #pragma unroll
    for (int t = 0; t < 8; ++t)
        #pragma unroll
        for (int n = 0; n < 4; ++n)
            #pragma unroll
            for (int g = 0; g < 4; ++g) {
                int row  = wm * 128 + t * 16 + q4 * 4 + g;
                int colb = (wn * 64 + n * 16 + l15) * 2;
                *(unsigned short*)((char*)smem + row * 512 + (colb ^ ((row & 7) << 4))) =
                    f2bf((acc[t][n][g] + bv[n]) * scale);
            }
    __syncthreads();
    {
        int rr = wave >> 2, c = wave & 3;            // slab = (jq half, col band)
        int jg = (mT * 2 + rr) * 16 + ((colBase & 1023) >> 6) + c;
        unsigned short* dstG = outb + (size_t)jg * 8192 + (lane & 7) * 8;
        #pragma unroll
        for (int it = 0; it < 16; ++it) {
            int i_na = it * 8 + (lane >> 3);
            int r = rr * 128 + i_na;
            int colb = (c * 128 + (lane & 7) * 16) ^ ((r & 7) << 4);
            short8v v = *(const short8v*)((const char*)smem + r * 512 + colb);
            *(short8v*)(dstG + (size_t)i_na * 64) = v;
        }
    }
}

// ---------------------------------------------------------------- K3: attention
// 4096 blocks (1 group), 128 threads (2 waves); wave wm owns query rows
// m in [wm*64, wm*64+64) x all 128 keys. All inputs are dense 16-KB slabs.
// LDS 51.2 KB (3 blocks/CU): sQ[16K] sK[16K] sVt[17408] csum[1K];
// P panel [128][256B] XOR-swizzled aliases sQ+sK after barrier 2.
__global__ __launch_bounds__(128) void k3_attn(const unsigned short* __restrict__ Qg,
                                               const unsigned short* __restrict__ Kg,
                                               const unsigned short* __restrict__ Vg,
                                               unsigned short* __restrict__ attnb,
                                               float* __restrict__ avgw) {
    __shared__ __attribute__((aligned(128))) char smem[51200];
    float* csum = (float*)(smem + 50176);            // [2][128]

    int j = blockIdx.x;
    int tid = threadIdx.x;
    int lane = tid & 63;
    int wm = tid >> 6;                               // wave = query half
    int q4 = lane >> 4, l15 = lane & 15;

    // Stage Q,K slabs via GLL: linear LDS dest, source col XOR-pre-swizzled
    // within the 128-B slab row (row&7 == lane>>3 within each 8-row GLL).
    {
        const char* qg = (const char*)(Qg + (size_t)j * 8192);
        const char* kg = (const char*)(Kg + (size_t)j * 8192);
        int swz = ((lane & 7) ^ (lane >> 3)) << 4;
        #pragma unroll
        for (int blk = 0; blk < 8; ++blk) {
            int row0 = wm * 64 + blk * 8;
            int src = (row0 + (lane >> 3)) * 128 + swz;
            GLL(qg + src, smem + row0 * 128);
            GLL(kg + src, smem + 16384 + row0 * 128);
        }
    }
    // V: in-register 8x8 transpose from dense slab -> sVt[64 d][272 B rows].
    {
        int nb = tid & 15, db = tid >> 4;            // db in [0,8)
        const unsigned short* vsrc = Vg + (size_t)j * 8192 + (nb * 8) * 64 + db * 8;
        short8v in[8];
        #pragma unroll
        for (int k = 0; k < 8; ++k) in[k] = *(const short8v*)(vsrc + k * 64);
        char* vt = smem + 32768;
        #pragma unroll
        for (int c = 0; c < 8; ++c) {
            short8v o;
            #pragma unroll
            for (int k = 0; k < 8; ++k) o[k] = in[k][c];
            *(short8v*)(vt + (db * 8 + c) * 272 + nb * 16) = o;
        }
    }
    __syncthreads();                                 // barrier 1

    // S'[n][m] = K Q^T: per-lane n = tn*16+q4*4+g, m = tm*16+l15 (+wm*64).
    float4v S[8][4];
    #pragma unroll
    for (int a = 0; a < 8; ++a)
        #pragma unroll
        for (int b = 0; b < 4; ++b) S[a][b] = (float4v){0.f, 0.f, 0.f, 0.f};
    #pragma unroll
    for (int ks = 0; ks < 2; ++ks) {
        int cb = (ks * 64 + q4 * 16) ^ ((l15 & 7) << 4);
        short8v qf[4];
        #pragma unroll
        for (int tm = 0; tm < 4; ++tm)
            qf[tm] = *(const short8v*)(smem + (wm * 64 + tm * 16 + l15) * 128 + cb);
        #pragma unroll
        for (int tn = 0; tn < 8; ++tn) {
            short8v kf = *(const short8v*)(smem + 16384 + (tn * 16 + l15) * 128 + cb);
            #pragma unroll
            for (int tm = 0; tm < 4; ++tm)
                S[tn][tm] = __builtin_amdgcn_mfma_f32_16x16x32_bf16(kf, qf[tm], S[tn][tm], 0, 0, 0);
        }
    }

    // In-wave softmax over keys n: in-lane reduce + shfl_xor(16,32) across q4.
    float rmax[4], inv[4];
    #pragma unroll
    for (int tm = 0; tm < 4; ++tm) {
        float m0 = S[0][tm][0];
        #pragma unroll
        for (int tn = 0; tn < 8; ++tn)
            #pragma unroll
            for (int g = 0; g < 4; ++g) m0 = fmaxf(m0, S[tn][tm][g]);
        m0 = fmaxf(m0, __shfl_xor(m0, 16, 64));
        m0 = fmaxf(m0, __shfl_xor(m0, 32, 64));
        rmax[tm] = m0;
    }
    #pragma unroll
    for (int tm = 0; tm < 4; ++tm) {
        float t0 = 0.f;
        #pragma unroll
        for (int tn = 0; tn < 8; ++tn)
            #pragma unroll
            for (int g = 0; g < 4; ++g) {
                float e = __expf(S[tn][tm][g] - rmax[tm]);
                S[tn][tm][g] = e;
                t0 += e;
            }
        t0 += __shfl_xor(t0, 16, 64);
        t0 += __shfl_xor(t0, 32, 64);
        inv[tm] = 1.0f / t0;
    }
    #pragma unroll
    for (int tn = 0; tn < 8; ++tn)
        #pragma unroll
        for (int tm = 0; tm < 4; ++tm)
            #pragma unroll
            for (int g = 0; g < 4; ++g) S[tn][tm][g] *= inv[tm];

    // avg_w partials: sum over m = in-lane over tm + shfl_xor(1,2,4,8) over l15.
    #pragma unroll
    for (int tn = 0; tn < 8; ++tn) {
        #pragma unroll
        for (int g = 0; g < 4; ++g) {
            float cs = S[tn][0][g] + S[tn][1][g] + S[tn][2][g] + S[tn][3][g];
            cs += __shfl_xor(cs, 1, 64);
            cs += __shfl_xor(cs, 2, 64);
            cs += __shfl_xor(cs, 4, 64);
            cs += __shfl_xor(cs, 8, 64);
            if (l15 == 0) csum[wm * 128 + tn * 16 + q4 * 4 + g] = cs;
        }
    }
    __syncthreads();                                 // barrier 2: sQ/sK reads done

    // P -> [128][256B] XOR-swizzled panel aliasing sQ+sK (wave-disjoint rows).
    char* sP = smem;
    #pragma unroll
    for (int tn = 0; tn < 8; ++tn)
        #pragma unroll
        for (int tm = 0; tm < 4; ++tm) {
            int row = wm * 64 + tm * 16 + l15;
            int swz = (row & 7) << 4;
            #pragma unroll
            for (int p = 0; p < 2; ++p) {
                unsigned int pk = pk_bf16(S[tn][tm][2 * p], S[tn][tm][2 * p + 1]);
                int x = ((tn * 16 + q4 * 4 + 2 * p) * 2) ^ swz;
                *(unsigned int*)(sP + row * 256 + x) = pk;
            }
        }

    // PV: O[m][d] = sum_n P[m][n] V^T[d][n]; pf from own P rows, vf from sVt.
    float4v O[4][4];
    #pragma unroll
    for (int a = 0; a < 4; ++a)
        #pragma unroll
        for (int b = 0; b < 4; ++b) O[a][b] = (float4v){0.f, 0.f, 0.f, 0.f};
    const char* vt = smem + 32768;
    #pragma unroll
    for (int ks = 0; ks < 4; ++ks) {
        int nB = (ks * 32 + q4 * 8) * 2;             // byte offset of n-chunk
        short8v pf[4], vf[4];
        #pragma unroll
        for (int t = 0; t < 4; ++t)
            vf[t] = *(const short8v*)(vt + (t * 16 + l15) * 272 + nB);
        #pragma unroll
        for (int tm = 0; tm < 4; ++tm) {
            int row = wm * 64 + tm * 16 + l15;
            pf[tm] = *(const short8v*)(sP + row * 256 + (nB ^ ((row & 7) << 4)));
        }
        #pragma unroll
        for (int tm = 0; tm < 4; ++tm)
            #pragma unroll
            for (int tno = 0; tno < 4; ++tno)
                O[tm][tno] = __builtin_amdgcn_mfma_f32_16x16x32_bf16(pf[tm], vf[tno], O[tm][tno], 0, 0, 0);
    }

    // Store O row-major: row m = i_na*256 + (j>>4), cols (j&15)*64 + d.
    {
        int jq = j >> 4;
        int eb = (j & 15) * 64;
        #pragma unroll
        for (int tm = 0; tm < 4; ++tm)
            #pragma unroll
            for (int g = 0; g < 4; ++g) {
                int i_na = wm * 64 + tm * 16 + q4 * 4 + g;
                size_t mrow = (size_t)i_na * 256 + jq;
                #pragma unroll
                for (int tno = 0; tno < 4; ++tno)
                    attnb[mrow * 1024 + eb + tno * 16 + l15] = f2bf(O[tm][tno][g]);
            }
    }

    __syncthreads();                                 // barrier 3: csum combine
    avgw[(size_t)j * 128 + tid] = (csum[tid] + csum[128 + tid]) * (1.0f / 16.0f);
}

// ---------------------------------------------------------------- K4: residual + LN2
__global__ __launch_bounds__(256) void k4_ln2(const float* __restrict__ x,
                                              const float* __restrict__ w1,
                                              const float* __restrict__ b1,
                                              const unsigned short* __restrict__ attnb,
                                              const float* __restrict__ w2,
                                              const float* __restrict__ b2,
                                              float* __restrict__ out) {
    __shared__ float red[8];
    int row = blockIdx.x;
    int tid = threadIdx.x;
    float4v xv = ((const float4v*)(x + (size_t)row * 1024))[tid];
    float s  = xv[0] + xv[1] + xv[2] + xv[3];
    float s2 = xv[0]*xv[0] + xv[1]*xv[1] + xv[2]*xv[2] + xv[3]*xv[3];
    block_reduce_2(s, s2, red);
    float mean = s * (1.0f / 1024.0f);
    float var  = s2 * (1.0f / 1024.0f) - mean * mean;
    float rs   = rsqrtf(var + LN_EPS);
    float4v wv = ((const float4v*)w1)[tid];
    float4v bv = ((const float4v*)b1)[tid];
    short4v av = ((const short4v*)(attnb + (size_t)row * 1024))[tid];
    float4v r;
    #pragma unroll
    for (int c = 0; c < 4; ++c)
        r[c] = (xv[c] - mean) * rs * wv[c] + bv[c] + bf2f((unsigned short)av[c]);
    s  = r[0] + r[1] + r[2] + r[3];
    s2 = r[0]*r[0] + r[1]*r[1] + r[2]*r[2] + r[3]*r[3];
    block_reduce_2(s, s2, red);
    float mean2 = s * (1.0f / 1024.0f);
    float var2  = s2 * (1.0f / 1024.0f) - mean2 * mean2;
    float rs2   = rsqrtf(var2 + LN_EPS);
    float4v w2v = ((const float4v*)w2)[tid];
    float4v b2v = ((const float4v*)b2)[tid];
    float4v o;
    #pragma unroll
    for (int c = 0; c < 4; ++c)
        o[c] = (r[c] - mean2) * rs2 * w2v[c] + b2v[c];
    ((float4v*)(out + (size_t)row * 1024))[tid] = o;
}

// ---------------------------------------------------------------- launch
extern "C" void kernel_launch(void* const* d_in, const int* in_sizes, int n_in,
                              void* d_out, int out_size, void* d_ws, size_t ws_size,
                              hipStream_t stream) {
    const float* x    = (const float*)d_in[0];
    const float* ln1w = (const float*)d_in[1];
    const float* ln1b = (const float*)d_in[2];
    const float* inw  = (const float*)d_in[3];
    const float* inb  = (const float*)d_in[4];
    const float* ln2w = (const float*)d_in[5];
    const float* ln2b = (const float*)d_in[6];
    float* out  = (float*)d_out;
    float* avgw = out + 33554432;           // 256*128*1024

    char* ws = (char*)d_ws;                 // needs ~275 MB
    unsigned short* xnb   = (unsigned short*)(ws);               // K2 input; then attnb
    unsigned short* attnb = (unsigned short*)(ws);               // overlays xnb (dead after K2)
    unsigned short* Qg    = (unsigned short*)(ws + 67108864);
    unsigned short* Kg    = (unsigned short*)(ws + 134217728);
    unsigned short* Vg    = (unsigned short*)(ws + 201326592);
    unsigned short* Wb    = (unsigned short*)(ws + 268435456);

    k0_w_to_bf16<<<1536, 256, 0, stream>>>(inw, Wb);
    k1_ln1<<<32768, 256, 0, stream>>>(x, ln1w, ln1b, xnb);
    k2_qkv_gemm<<<1536, 512, 0, stream>>>(xnb, Wb, inb, Qg, Kg, Vg);
    k3_attn<<<4096, 128, 0, stream>>>(Qg, Kg, Vg, attnb, avgw);
    k4_ln2<<<32768, 256, 0, stream>>>(x, ln1w, ln1b, attnb, ln2w, ln2b, out);
}